// Round 10
// baseline (203.313 us; speedup 1.0000x reference)
//
#include <hip/hip_runtime.h>

#define B_     8
#define CIN_   512
#define COUT_  512
#define HW_    64
#define SDIM_  512
#define NPIX   4096      // pixels per image
#define KTOT   4608      // 9*512
#define PADW   66

typedef __attribute__((ext_vector_type(4))) float f32x4;
typedef __attribute__((ext_vector_type(16))) float f32x16;
typedef __attribute__((ext_vector_type(8))) short bf16x8;
typedef __attribute__((ext_vector_type(8))) unsigned short u16x8;

__device__ __forceinline__ float bf2f(unsigned short b) {
    unsigned int u = ((unsigned int)b) << 16;
    return __builtin_bit_cast(float, u);
}
__device__ __forceinline__ unsigned short f2bf(float f) {
    unsigned int u = __builtin_bit_cast(unsigned int, f);
    return (unsigned short)((u + 0x7fffu + ((u >> 16) & 1u)) >> 16);
}
__device__ __forceinline__ float ldin(const void* p, size_t i, int isbf) {
    return isbf ? bf2f(((const unsigned short*)p)[i]) : ((const float*)p)[i];
}

#define GLD16(g, l) __builtin_amdgcn_global_load_lds( \
    (__attribute__((address_space(1))) void*)(g),     \
    (__attribute__((address_space(3))) void*)(l), 16, 0, 0)

// ---------------- dtype detection (unchanged, verified) ----------------
__global__ void detect_dtype(const unsigned int* __restrict__ style_u32,
                             int* __restrict__ flag) {
    int t = threadIdx.x;
    unsigned int w = style_u32[t * 4];
    int e = (w >> 7) & 0xFF;
    int isbf = (e >= 110 && e <= 140) ? 1 : 0;
    __shared__ int cnt;
    if (t == 0) cnt = 0;
    __syncthreads();
    atomicAdd(&cnt, isbf);
    __syncthreads();
    if (t == 0) *flag = (cnt >= 128) ? 1 : 0;
}

// ---------------- zero only the halo ring of xtp ----------------
__global__ void halo_zero(unsigned short* __restrict__ xtp) {
    int idx = blockIdx.x;        // 0..259
    int b = blockIdx.y;
    int y, x;
    if (idx < 66)       { y = 0;  x = idx; }
    else if (idx < 132) { y = 65; x = idx - 66; }
    else if (idx < 196) { x = 0;  y = idx - 131; }
    else                { x = 65; y = idx - 195; }
    unsigned int* dst = (unsigned int*)(xtp + (((size_t)b * PADW + y) * PADW + x) * CIN_);
    dst[threadIdx.x] = 0;
}

// ---------------- kernel (k,co) -> Wt (co,k) transpose (unchanged) ----------------
__global__ void wt_transpose(const void* __restrict__ kin,
                             unsigned short* __restrict__ wt,
                             const int* __restrict__ flag) {
    __shared__ __align__(16) unsigned short tile[64][72];
    int isbf = *flag;
    int t = threadIdx.x;
    int co0 = blockIdx.x * 64;
    int k0  = blockIdx.y * 64;
    int r = t >> 2, c16 = (t & 3) << 4;
    if (isbf) {
        const unsigned short* src = (const unsigned short*)kin + (size_t)(k0 + r) * COUT_ + co0 + c16;
        *(u16x8*)&tile[r][c16]     = *(const u16x8*)src;
        *(u16x8*)&tile[r][c16 + 8] = *(const u16x8*)(src + 8);
    } else {
        const float* src = (const float*)kin + (size_t)(k0 + r) * COUT_ + co0 + c16;
#pragma unroll
        for (int q = 0; q < 4; ++q) {
            f32x4 v = *(const f32x4*)(src + q * 4);
#pragma unroll
            for (int j = 0; j < 4; ++j) tile[r][c16 + q * 4 + j] = f2bf(v[j]);
        }
    }
    __syncthreads();
    int c = t >> 2, r16 = (t & 3) << 4;
    u16x8 w0, w1;
#pragma unroll
    for (int j = 0; j < 8; ++j) { w0[j] = tile[r16 + j][c]; w1[j] = tile[r16 + 8 + j][c]; }
    unsigned short* dst = wt + (size_t)(co0 + c) * KTOT + k0 + r16;
    *(u16x8*)dst       = w0;
    *(u16x8*)(dst + 8) = w1;
}

// ---------------- x NCHW -> padded bf16 NHWC (unchanged) ----------------
__global__ void xpose(const void* __restrict__ x,
                      unsigned short* __restrict__ xtp,
                      const int* __restrict__ flag) {
    __shared__ __align__(16) unsigned short tile[64][72];
    int isbf = *flag;
    int t = threadIdx.x;
    int cit = blockIdx.x;
    int y   = blockIdx.y;
    int b   = blockIdx.z;
    int ci_l = t >> 2, xo = (t & 3) << 4;
    size_t srcoff = (((size_t)(b * CIN_ + cit * 64 + ci_l)) * HW_ + y) * HW_ + xo;
    if (isbf) {
        const unsigned short* src = (const unsigned short*)x + srcoff;
        *(u16x8*)&tile[ci_l][xo]     = *(const u16x8*)src;
        *(u16x8*)&tile[ci_l][xo + 8] = *(const u16x8*)(src + 8);
    } else {
        const float* src = (const float*)x + srcoff;
#pragma unroll
        for (int q = 0; q < 4; ++q) {
            f32x4 v = *(const f32x4*)(src + q * 4);
#pragma unroll
            for (int j = 0; j < 4; ++j) tile[ci_l][xo + q * 4 + j] = f2bf(v[j]);
        }
    }
    __syncthreads();
    int xl = t >> 2, cio = (t & 3) << 4;
    u16x8 w0, w1;
#pragma unroll
    for (int j = 0; j < 8; ++j) { w0[j] = tile[cio + j][xl]; w1[j] = tile[cio + 8 + j][xl]; }
    unsigned short* dst =
        xtp + (((size_t)b * PADW + (y + 1)) * PADW + (xl + 1)) * CIN_ + cit * 64 + cio;
    *(u16x8*)dst       = w0;
    *(u16x8*)(dst + 8) = w1;
}

// ---------------- mod scale (unchanged) ----------------
__global__ void mod_kernel(const void* __restrict__ style,
                           const void* __restrict__ sscale,
                           const unsigned short* __restrict__ wt,
                           float* __restrict__ mmod,
                           const int* __restrict__ flag) {
    int isbf = *flag;
    int co = blockIdx.x, t = threadIdx.x;
    int lane = t & 63, wid = t >> 6;
    float k2 = 0.f;
    const unsigned short* wr = wt + (size_t)co * KTOT;
    for (int k = t; k < KTOT; k += 256) { float v = bf2f(wr[k]); k2 += v * v; }
    float sb[B_];
#pragma unroll
    for (int b = 0; b < B_; ++b) sb[b] = 0.f;
    for (int sd = t; sd < SDIM_; sd += 256) {
        float ss = ldin(sscale, (size_t)sd * COUT_ + co, isbf);
#pragma unroll
        for (int b = 0; b < B_; ++b) sb[b] += ldin(style, b * SDIM_ + sd, isbf) * ss;
    }
    __shared__ float red[4][9];
    float vals[9];
    vals[0] = k2;
#pragma unroll
    for (int b = 0; b < B_; ++b) vals[1 + b] = sb[b];
#pragma unroll
    for (int q = 0; q < 9; ++q) {
        float v = vals[q];
        for (int off = 32; off; off >>= 1) v += __shfl_down(v, off);
        if (lane == 0) red[wid][q] = v;
    }
    __syncthreads();
    if (t < B_) {
        int b = t;
        float k2t = red[0][0] + red[1][0] + red[2][0] + red[3][0];
        float s   = red[0][1 + b] + red[1][1 + b] + red[2][1 + b] + red[3][1 + b];
        float sp1 = s + 1.f;
        mmod[b * COUT_ + co] = sp1 * rsqrtf(sp1 * sp1 * k2t + 1e-8f);
    }
}

// ---------------- implicit-GEMM conv, 256x256, 8 waves, 32x32x16 MFMA ----------------
// R9 drift structure (1 barrier/K-tile) with the 32x32x16 shape: half the MFMA
// instructions at 2x FLOP each (higher ubench ceiling 2382 vs 2075 TF), same
// LDS bytes, same staging/swizzle. Fragment maps: A row=lane&31, k=(lane>>5)*8+j;
// C/D col=lane&31 (pix), row=(reg&3)+8*(reg>>2)+4*(lane>>5) (co).
__global__ __launch_bounds__(512, 2) void conv_gemm(
    const unsigned short* __restrict__ wt,
    const unsigned short* __restrict__ xtp,
    const float* __restrict__ mmod,
    const void* __restrict__ noise,
    const void* __restrict__ bias,
    const void* __restrict__ nwp,
    void* __restrict__ out,
    const int* __restrict__ flag) {
    __shared__ __align__(1024) unsigned short Asm[2][256 * 64];   // 64 KiB
    __shared__ __align__(1024) unsigned short Bsm[2][256 * 64];   // 64 KiB
    int isbf = *flag;
    int tid = threadIdx.x;
    int lane = tid & 63, wid = tid >> 6;
    int l31 = lane & 31, hi2 = lane >> 5;
    int wm = wid >> 2, wn = wid & 3;          // 2 x 4 wave grid; wave tile 128co x 64pix

    int bid = blockIdx.x;
    int swz = (bid & 7) * 32 + (bid >> 3);    // XCD-chunked bijective (256 % 8 == 0)
    int gy = swz >> 7;
    int nb = swz & 127;
    int b  = nb >> 4;
    int nt = nb & 15;
    int pl0 = nt << 8;                        // 256 pixels = 4 rows
    int h0  = pl0 >> 6;
    int co0 = gy << 8;

    const unsigned short* xb = xtp + (size_t)b * (PADW * PADW * CIN_);

    f32x16 acc[4][2];
#pragma unroll
    for (int i = 0; i < 4; ++i)
#pragma unroll
        for (int j = 0; j < 2; ++j)
#pragma unroll
            for (int e = 0; e < 16; ++e) acc[i][j][e] = 0.f;

    int rsub = lane >> 3;
    int ce_src = ((lane & 7) ^ rsub) << 3;    // pre-swizzled source column (elements)
    int swzr = (lane & 7) << 3;               // read-side XOR (row&7 == lane&7 for 32-row frags too)

    auto stageA = [&](int tt, int pp, int q) {
        const unsigned short* srcA =
            wt + (size_t)(co0 + (q << 6) + (wid << 3) + rsub) * KTOT + (tt << 6) + ce_src;
        GLD16(srcA, (char*)&Asm[pp][0] + (q << 13) + (wid << 10));
    };
    auto stageB = [&](int tt, int pp, int q) {
        int khw = tt >> 3;
        int kh = (khw >= 6) ? 2 : ((khw >= 3) ? 1 : 0);
        int kw = khw - kh * 3;
        int ci0 = (tt & 7) << 6;
        int wc = ((wid << 3) + rsub) & 63;
        const unsigned short* srcB =
            xb + ((size_t)(h0 + q + kh) * PADW + (wc + kw)) * CIN_ + ci0 + ce_src;
        GLD16(srcB, (char*)&Bsm[pp][0] + (q << 13) + (wid << 10));
    };

    // prologue: tile 0 staged, drained, synced
#pragma unroll
    for (int q = 0; q < 4; ++q) { stageA(0, 0, q); stageB(0, 0, q); }
    asm volatile("s_waitcnt vmcnt(0)" ::: "memory");
    __builtin_amdgcn_s_barrier();
    asm volatile("" ::: "memory");

    for (int t = 0; t < 72; ++t) {
        int p = t & 1, pn = p ^ 1;
        const unsigned short* As = &Asm[p][0];
        const unsigned short* Bs = &Bsm[p][0];

        // stage ALL of tile t+1 into pn (its readers retired one fence+barrier ago)
        if (t < 71) {
#pragma unroll
            for (int q = 0; q < 4; ++q) { stageA(t + 1, pn, q); stageB(t + 1, pn, q); }
        }

        // 4 K-quadrants (kq: 16 k each); per kq: 4 A-frags + 2 B-frags, 8 MFMA
#pragma unroll
        for (int kq = 0; kq < 4; ++kq) {
            int ke = (kq << 4) + (hi2 << 3);   // element column base for this lane
            bf16x8 a[4], bv[2];
#pragma unroll
            for (int mi = 0; mi < 4; ++mi)
                a[mi] = *(const bf16x8*)&As[(((wm << 7) + (mi << 5) + l31) << 6) + (ke ^ swzr)];
#pragma unroll
            for (int ni = 0; ni < 2; ++ni)
                bv[ni] = *(const bf16x8*)&Bs[(((wn << 6) + (ni << 5) + l31) << 6) + (ke ^ swzr)];
            __builtin_amdgcn_s_setprio(1);
#pragma unroll
            for (int mi = 0; mi < 4; ++mi)
#pragma unroll
                for (int ni = 0; ni < 2; ++ni)
                    acc[mi][ni] = __builtin_amdgcn_mfma_f32_32x32x16_bf16(
                        a[mi], bv[ni], acc[mi][ni], 0, 0, 0);
            __builtin_amdgcn_s_setprio(0);
        }

        // ---- tile boundary: 2 fences + 1 barrier ----
        asm volatile("s_waitcnt lgkmcnt(0)" ::: "memory");   // my reads of p retired
        if (t < 71) asm volatile("s_waitcnt vmcnt(0)" ::: "memory");  // t+1 landed (full-tile lead)
        __builtin_amdgcn_s_barrier();
        asm volatile("" ::: "memory");                        // pin next stages below barrier
    }

    // fused epilogue: out = leaky(m*y + nw*noise + bias) * sqrt(2), NCHW
    float nw = ldin(nwp, 0, isbf);
    unsigned short* out16 = (unsigned short*)out;
    float* outf = (float*)out;
#pragma unroll
    for (int mi = 0; mi < 4; ++mi) {
#pragma unroll
        for (int ni = 0; ni < 2; ++ni) {
            int pix = pl0 + (wn << 6) + (ni << 5) + l31;
            float nv = nw * ldin(noise, b * NPIX + pix, isbf);
#pragma unroll
            for (int q = 0; q < 4; ++q) {
                int cob = co0 + (wm << 7) + (mi << 5) + (q << 3) + (hi2 << 2);
                f32x4 mv = *(const f32x4*)&mmod[b * COUT_ + cob];
                float bb[4];
#pragma unroll
                for (int r = 0; r < 4; ++r) bb[r] = ldin(bias, cob + r, isbf);
#pragma unroll
                for (int r = 0; r < 4; ++r) {
                    float v = acc[mi][ni][q * 4 + r] * mv[r] + nv + bb[r];
                    v = (v < 0.f ? v * 0.2f : v) * 1.41421356237f;
                    size_t oidx = ((size_t)(b * COUT_ + cob + r)) * NPIX + pix;
                    if (isbf) out16[oidx] = f2bf(v);
                    else      outf[oidx]  = v;
                }
            }
        }
    }
}

extern "C" void kernel_launch(void* const* d_in, const int* in_sizes, int n_in,
                              void* d_out, int out_size, void* d_ws, size_t ws_size,
                              hipStream_t stream) {
    const void* x      = d_in[0];
    const void* style  = d_in[1];
    const void* noise  = d_in[2];
    const void* kin    = d_in[3];
    const void* sscale = d_in[4];
    const void* bias   = d_in[5];
    const void* nwp    = d_in[6];

    char* ws = (char*)d_ws;
    int* flag = (int*)ws;
    const size_t xtp_off  = 256;
    const size_t xtp_bytes = (size_t)B_ * PADW * PADW * CIN_ * 2;
    const size_t wt_bytes  = (size_t)COUT_ * KTOT * 2;
    unsigned short* xtp = (unsigned short*)(ws + xtp_off);
    unsigned short* wtr = (unsigned short*)(ws + xtp_off + xtp_bytes);
    float* mmod         = (float*)(ws + xtp_off + xtp_bytes + wt_bytes);

    detect_dtype<<<1, 256, 0, stream>>>((const unsigned int*)style, flag);
    halo_zero<<<dim3(260, 8), 256, 0, stream>>>(xtp);
    wt_transpose<<<dim3(8, 72), 256, 0, stream>>>(kin, wtr, flag);
    xpose<<<dim3(8, 64, 8), 256, 0, stream>>>(x, xtp, flag);
    mod_kernel<<<512, 256, 0, stream>>>(style, sscale, wtr, mmod, flag);
    conv_gemm<<<256, 512, 0, stream>>>(wtr, xtp, mmod, noise, bias, nwp, d_out, flag);
}

// Round 11
// 188.248 us; speedup vs baseline: 1.0800x; 1.0800x over previous
//
#include <hip/hip_runtime.h>

#define B_     8
#define CIN_   512
#define COUT_  512
#define HW_    64
#define SDIM_  512
#define NPIX   4096      // pixels per image
#define KTOT   4608      // 9*512
#define PADW   66

typedef __attribute__((ext_vector_type(4))) float f32x4;
typedef __attribute__((ext_vector_type(8))) short bf16x8;
typedef __attribute__((ext_vector_type(8))) unsigned short u16x8;

__device__ __forceinline__ float bf2f(unsigned short b) {
    unsigned int u = ((unsigned int)b) << 16;
    return __builtin_bit_cast(float, u);
}
__device__ __forceinline__ unsigned short f2bf(float f) {
    unsigned int u = __builtin_bit_cast(unsigned int, f);
    return (unsigned short)((u + 0x7fffu + ((u >> 16) & 1u)) >> 16);
}
__device__ __forceinline__ float ldin(const void* p, size_t i, int isbf) {
    return isbf ? bf2f(((const unsigned short*)p)[i]) : ((const float*)p)[i];
}

#define GLD16(g, l) __builtin_amdgcn_global_load_lds( \
    (__attribute__((address_space(1))) void*)(g),     \
    (__attribute__((address_space(3))) void*)(l), 16, 0, 0)

// ---------------- dtype detection (unchanged, verified) ----------------
__global__ void detect_dtype(const unsigned int* __restrict__ style_u32,
                             int* __restrict__ flag) {
    int t = threadIdx.x;
    unsigned int w = style_u32[t * 4];
    int e = (w >> 7) & 0xFF;
    int isbf = (e >= 110 && e <= 140) ? 1 : 0;
    __shared__ int cnt;
    if (t == 0) cnt = 0;
    __syncthreads();
    atomicAdd(&cnt, isbf);
    __syncthreads();
    if (t == 0) *flag = (cnt >= 128) ? 1 : 0;
}

// ---------------- zero only the halo ring of xtp ----------------
__global__ void halo_zero(unsigned short* __restrict__ xtp) {
    int idx = blockIdx.x;        // 0..259
    int b = blockIdx.y;
    int y, x;
    if (idx < 66)       { y = 0;  x = idx; }
    else if (idx < 132) { y = 65; x = idx - 66; }
    else if (idx < 196) { x = 0;  y = idx - 131; }
    else                { x = 65; y = idx - 195; }
    unsigned int* dst = (unsigned int*)(xtp + (((size_t)b * PADW + y) * PADW + x) * CIN_);
    dst[threadIdx.x] = 0;
}

// ---------------- kernel (k,co) -> Wt (co,k) transpose (unchanged) ----------------
__global__ void wt_transpose(const void* __restrict__ kin,
                             unsigned short* __restrict__ wt,
                             const int* __restrict__ flag) {
    __shared__ __align__(16) unsigned short tile[64][72];
    int isbf = *flag;
    int t = threadIdx.x;
    int co0 = blockIdx.x * 64;
    int k0  = blockIdx.y * 64;
    int r = t >> 2, c16 = (t & 3) << 4;
    if (isbf) {
        const unsigned short* src = (const unsigned short*)kin + (size_t)(k0 + r) * COUT_ + co0 + c16;
        *(u16x8*)&tile[r][c16]     = *(const u16x8*)src;
        *(u16x8*)&tile[r][c16 + 8] = *(const u16x8*)(src + 8);
    } else {
        const float* src = (const float*)kin + (size_t)(k0 + r) * COUT_ + co0 + c16;
#pragma unroll
        for (int q = 0; q < 4; ++q) {
            f32x4 v = *(const f32x4*)(src + q * 4);
#pragma unroll
            for (int j = 0; j < 4; ++j) tile[r][c16 + q * 4 + j] = f2bf(v[j]);
        }
    }
    __syncthreads();
    int c = t >> 2, r16 = (t & 3) << 4;
    u16x8 w0, w1;
#pragma unroll
    for (int j = 0; j < 8; ++j) { w0[j] = tile[r16 + j][c]; w1[j] = tile[r16 + 8 + j][c]; }
    unsigned short* dst = wt + (size_t)(co0 + c) * KTOT + k0 + r16;
    *(u16x8*)dst       = w0;
    *(u16x8*)(dst + 8) = w1;
}

// ---------------- x NCHW -> padded bf16 NHWC (unchanged) ----------------
__global__ void xpose(const void* __restrict__ x,
                      unsigned short* __restrict__ xtp,
                      const int* __restrict__ flag) {
    __shared__ __align__(16) unsigned short tile[64][72];
    int isbf = *flag;
    int t = threadIdx.x;
    int cit = blockIdx.x;
    int y   = blockIdx.y;
    int b   = blockIdx.z;
    int ci_l = t >> 2, xo = (t & 3) << 4;
    size_t srcoff = (((size_t)(b * CIN_ + cit * 64 + ci_l)) * HW_ + y) * HW_ + xo;
    if (isbf) {
        const unsigned short* src = (const unsigned short*)x + srcoff;
        *(u16x8*)&tile[ci_l][xo]     = *(const u16x8*)src;
        *(u16x8*)&tile[ci_l][xo + 8] = *(const u16x8*)(src + 8);
    } else {
        const float* src = (const float*)x + srcoff;
#pragma unroll
        for (int q = 0; q < 4; ++q) {
            f32x4 v = *(const f32x4*)(src + q * 4);
#pragma unroll
            for (int j = 0; j < 4; ++j) tile[ci_l][xo + q * 4 + j] = f2bf(v[j]);
        }
    }
    __syncthreads();
    int xl = t >> 2, cio = (t & 3) << 4;
    u16x8 w0, w1;
#pragma unroll
    for (int j = 0; j < 8; ++j) { w0[j] = tile[cio + j][xl]; w1[j] = tile[cio + 8 + j][xl]; }
    unsigned short* dst =
        xtp + (((size_t)b * PADW + (y + 1)) * PADW + (xl + 1)) * CIN_ + cit * 64 + cio;
    *(u16x8*)dst       = w0;
    *(u16x8*)(dst + 8) = w1;
}

// ---------------- mod scale (unchanged) ----------------
__global__ void mod_kernel(const void* __restrict__ style,
                           const void* __restrict__ sscale,
                           const unsigned short* __restrict__ wt,
                           float* __restrict__ mmod,
                           const int* __restrict__ flag) {
    int isbf = *flag;
    int co = blockIdx.x, t = threadIdx.x;
    int lane = t & 63, wid = t >> 6;
    float k2 = 0.f;
    const unsigned short* wr = wt + (size_t)co * KTOT;
    for (int k = t; k < KTOT; k += 256) { float v = bf2f(wr[k]); k2 += v * v; }
    float sb[B_];
#pragma unroll
    for (int b = 0; b < B_; ++b) sb[b] = 0.f;
    for (int sd = t; sd < SDIM_; sd += 256) {
        float ss = ldin(sscale, (size_t)sd * COUT_ + co, isbf);
#pragma unroll
        for (int b = 0; b < B_; ++b) sb[b] += ldin(style, b * SDIM_ + sd, isbf) * ss;
    }
    __shared__ float red[4][9];
    float vals[9];
    vals[0] = k2;
#pragma unroll
    for (int b = 0; b < B_; ++b) vals[1 + b] = sb[b];
#pragma unroll
    for (int q = 0; q < 9; ++q) {
        float v = vals[q];
        for (int off = 32; off; off >>= 1) v += __shfl_down(v, off);
        if (lane == 0) red[wid][q] = v;
    }
    __syncthreads();
    if (t < B_) {
        int b = t;
        float k2t = red[0][0] + red[1][0] + red[2][0] + red[3][0];
        float s   = red[0][1 + b] + red[1][1 + b] + red[2][1 + b] + red[3][1 + b];
        float sp1 = s + 1.f;
        mmod[b * COUT_ + co] = sp1 * rsqrtf(sp1 * sp1 * k2t + 1e-8f);
    }
}

// ---------------- implicit-GEMM conv: m201 8-phase port ----------------
// 256x256, BK=64, 8 waves (2Mx4N), 16x16x32 MFMA. Iter = 2 K-tiles (X=buf0, Y=buf1).
// Phase = {ds_reads | stage 1 half-tile (2 gld16) | [lgkm(8) if 12 reads] | bar |
//          lgkm(0) | setprio1 | 16 MFMA | setprio0 | [vmcnt(4) ph4/ph8] | bar | fence}
// Stage ring: ph1 A1(2i+1)->Y  ph2 B1(2i+1)->Y  ph3 B0(2i+2)->X  ph4 A0(2i+2)->X
//             ph5 B1(2i+2)->X  ph6 A1(2i+2)->X  ph7 B0(2i+3)->Y  ph8 A0(2i+3)->Y
// vmcnt(4) leaves exactly the 2 newest half-tiles in flight; every half-tile
// confirmed >=1 phase before first read; every stage >=2 fences after last read.
__global__ __launch_bounds__(512, 2) void conv_gemm(
    const unsigned short* __restrict__ wt,
    const unsigned short* __restrict__ xtp,
    const float* __restrict__ mmod,
    const void* __restrict__ noise,
    const void* __restrict__ bias,
    const void* __restrict__ nwp,
    void* __restrict__ out,
    const int* __restrict__ flag) {
    __shared__ __align__(1024) unsigned short Asm[2][256 * 64];   // 64 KiB
    __shared__ __align__(1024) unsigned short Bsm[2][256 * 64];   // 64 KiB
    int isbf = *flag;
    int tid = threadIdx.x;
    int lane = tid & 63, wid = tid >> 6;
    int lr = lane & 15, hi = lane >> 4;
    int wm = wid >> 2, wn = wid & 3;          // 2 x 4 wave grid

    int bid = blockIdx.x;
    int swz = (bid & 7) * 32 + (bid >> 3);    // XCD-chunked bijective (256 % 8 == 0)
    int gy = swz >> 7;
    int nb = swz & 127;
    int b  = nb >> 4;
    int nt = nb & 15;
    int pl0 = nt << 8;                        // 256 pixels = 4 rows
    int h0  = pl0 >> 6;
    int co0 = gy << 8;

    const unsigned short* xb = xtp + (size_t)b * (PADW * PADW * CIN_);

    f32x4 acc[8][4];
#pragma unroll
    for (int i = 0; i < 8; ++i)
#pragma unroll
        for (int j = 0; j < 4; ++j) acc[i][j] = (f32x4){0.f, 0.f, 0.f, 0.f};

    int rsub = lane >> 3;
    int ce_src = ((lane & 7) ^ rsub) << 3;    // pre-swizzled source column (elements)
    int swzr = (lane & 7) << 3;               // read-side XOR

    auto stageA = [&](int tt, int pp, int q) {
        const unsigned short* srcA =
            wt + (size_t)(co0 + (q << 6) + (wid << 3) + rsub) * KTOT + (tt << 6) + ce_src;
        GLD16(srcA, (char*)&Asm[pp][0] + (q << 13) + (wid << 10));
    };
    auto stageB = [&](int tt, int pp, int q) {
        int khw = tt >> 3;
        int kh = (khw >= 6) ? 2 : ((khw >= 3) ? 1 : 0);
        int kw = khw - kh * 3;
        int ci0 = (tt & 7) << 6;
        int wc = ((wid << 3) + rsub) & 63;
        const unsigned short* srcB =
            xb + ((size_t)(h0 + q + kh) * PADW + (wc + kw)) * CIN_ + ci0 + ce_src;
        GLD16(srcB, (char*)&Bsm[pp][0] + (q << 13) + (wid << 10));
    };
    auto rdA = [&](const unsigned short* Bp, int mi, int kk) -> bf16x8 {
        return *(const bf16x8*)&Bp[(((wm << 7) + (mi << 4) + lr) << 6) +
                                   (((kk << 5) + (hi << 3)) ^ swzr)];
    };
    auto rdB = [&](const unsigned short* Bp, int ni, int kk) -> bf16x8 {
        return *(const bf16x8*)&Bp[(((wn << 6) + (ni << 4) + lr) << 6) +
                                   (((kk << 5) + (hi << 3)) ^ swzr)];
    };

#define PH_SYNC12  asm volatile("s_waitcnt lgkmcnt(8)" ::: "memory");
#define PH_TOP     __builtin_amdgcn_s_barrier(); \
                   asm volatile("s_waitcnt lgkmcnt(0)" ::: "memory"); \
                   __builtin_amdgcn_s_setprio(1);
#define PH_END     __builtin_amdgcn_s_setprio(0);
#define PH_BAR     __builtin_amdgcn_s_barrier(); asm volatile("" ::: "memory");

    // prologue: X(t0) full, Y(t1) {B0,A0}; vmcnt(4) -> X landed, Y's 4 in flight
#pragma unroll
    for (int q = 0; q < 4; ++q) { stageA(0, 0, q); stageB(0, 0, q); }
    stageB(1, 1, 0); stageB(1, 1, 1); stageA(1, 1, 0); stageA(1, 1, 1);
    asm volatile("s_waitcnt vmcnt(4)" ::: "memory");
    __builtin_amdgcn_s_barrier();
    asm volatile("" ::: "memory");

    for (int i = 0; i < 36; ++i) {
        int tY = 2 * i + 1;
        bool sg = (i < 35);
        const unsigned short* Xa = &Asm[0][0];
        const unsigned short* Xb = &Bsm[0][0];
        const unsigned short* Ya = &Asm[1][0];
        const unsigned short* Yb = &Bsm[1][0];
        bf16x8 aL[4][2], aH[4][2], bL[2][2], bR[2][2];

        // ======== K-tile X = 2i (buf0) ========
        // ph1: read aL,bL ; stage A1(tY)->Y
#pragma unroll
        for (int mi = 0; mi < 4; ++mi) { aL[mi][0] = rdA(Xa, mi, 0); aL[mi][1] = rdA(Xa, mi, 1); }
#pragma unroll
        for (int ni = 0; ni < 2; ++ni) { bL[ni][0] = rdB(Xb, ni, 0); bL[ni][1] = rdB(Xb, ni, 1); }
        stageA(tY, 1, 2); stageA(tY, 1, 3);
        PH_SYNC12
        PH_TOP
#pragma unroll
        for (int mi = 0; mi < 4; ++mi)
#pragma unroll
            for (int ni = 0; ni < 2; ++ni) {
                acc[mi][ni] = __builtin_amdgcn_mfma_f32_16x16x32_bf16(aL[mi][0], bL[ni][0], acc[mi][ni], 0, 0, 0);
                acc[mi][ni] = __builtin_amdgcn_mfma_f32_16x16x32_bf16(aL[mi][1], bL[ni][1], acc[mi][ni], 0, 0, 0);
            }
        PH_END
        PH_BAR

        // ph2: read bR ; stage B1(tY)->Y
#pragma unroll
        for (int ni = 0; ni < 2; ++ni) { bR[ni][0] = rdB(Xb, ni + 2, 0); bR[ni][1] = rdB(Xb, ni + 2, 1); }
        stageB(tY, 1, 2); stageB(tY, 1, 3);
        PH_TOP
#pragma unroll
        for (int mi = 0; mi < 4; ++mi)
#pragma unroll
            for (int ni = 0; ni < 2; ++ni) {
                acc[mi][ni + 2] = __builtin_amdgcn_mfma_f32_16x16x32_bf16(aL[mi][0], bR[ni][0], acc[mi][ni + 2], 0, 0, 0);
                acc[mi][ni + 2] = __builtin_amdgcn_mfma_f32_16x16x32_bf16(aL[mi][1], bR[ni][1], acc[mi][ni + 2], 0, 0, 0);
            }
        PH_END
        PH_BAR

        // ph3: read aH ; stage B0(2i+2)->X
#pragma unroll
        for (int mi = 0; mi < 4; ++mi) { aH[mi][0] = rdA(Xa, mi + 4, 0); aH[mi][1] = rdA(Xa, mi + 4, 1); }
        if (sg) { stageB(2 * i + 2, 0, 0); stageB(2 * i + 2, 0, 1); }
        PH_TOP
#pragma unroll
        for (int mi = 0; mi < 4; ++mi)
#pragma unroll
            for (int ni = 0; ni < 2; ++ni) {
                acc[mi + 4][ni] = __builtin_amdgcn_mfma_f32_16x16x32_bf16(aH[mi][0], bL[ni][0], acc[mi + 4][ni], 0, 0, 0);
                acc[mi + 4][ni] = __builtin_amdgcn_mfma_f32_16x16x32_bf16(aH[mi][1], bL[ni][1], acc[mi + 4][ni], 0, 0, 0);
            }
        PH_END
        PH_BAR

        // ph4: stage A0(2i+2)->X ; vmcnt
        if (sg) { stageA(2 * i + 2, 0, 0); stageA(2 * i + 2, 0, 1); }
        PH_TOP
#pragma unroll
        for (int mi = 0; mi < 4; ++mi)
#pragma unroll
            for (int ni = 0; ni < 2; ++ni) {
                acc[mi + 4][ni + 2] = __builtin_amdgcn_mfma_f32_16x16x32_bf16(aH[mi][0], bR[ni][0], acc[mi + 4][ni + 2], 0, 0, 0);
                acc[mi + 4][ni + 2] = __builtin_amdgcn_mfma_f32_16x16x32_bf16(aH[mi][1], bR[ni][1], acc[mi + 4][ni + 2], 0, 0, 0);
            }
        PH_END
        if (sg) asm volatile("s_waitcnt vmcnt(4)" ::: "memory");
        else    asm volatile("s_waitcnt vmcnt(0)" ::: "memory");
        PH_BAR

        // ======== K-tile Y = 2i+1 (buf1) ========
        // ph5: read aL,bL (Y) ; stage B1(2i+2)->X
#pragma unroll
        for (int mi = 0; mi < 4; ++mi) { aL[mi][0] = rdA(Ya, mi, 0); aL[mi][1] = rdA(Ya, mi, 1); }
#pragma unroll
        for (int ni = 0; ni < 2; ++ni) { bL[ni][0] = rdB(Yb, ni, 0); bL[ni][1] = rdB(Yb, ni, 1); }
        if (sg) { stageB(2 * i + 2, 0, 2); stageB(2 * i + 2, 0, 3); }
        PH_SYNC12
        PH_TOP
#pragma unroll
        for (int mi = 0; mi < 4; ++mi)
#pragma unroll
            for (int ni = 0; ni < 2; ++ni) {
                acc[mi][ni] = __builtin_amdgcn_mfma_f32_16x16x32_bf16(aL[mi][0], bL[ni][0], acc[mi][ni], 0, 0, 0);
                acc[mi][ni] = __builtin_amdgcn_mfma_f32_16x16x32_bf16(aL[mi][1], bL[ni][1], acc[mi][ni], 0, 0, 0);
            }
        PH_END
        PH_BAR

        // ph6: read bR (Y) ; stage A1(2i+2)->X
#pragma unroll
        for (int ni = 0; ni < 2; ++ni) { bR[ni][0] = rdB(Yb, ni + 2, 0); bR[ni][1] = rdB(Yb, ni + 2, 1); }
        if (sg) { stageA(2 * i + 2, 0, 2); stageA(2 * i + 2, 0, 3); }
        PH_TOP
#pragma unroll
        for (int mi = 0; mi < 4; ++mi)
#pragma unroll
            for (int ni = 0; ni < 2; ++ni) {
                acc[mi][ni + 2] = __builtin_amdgcn_mfma_f32_16x16x32_bf16(aL[mi][0], bR[ni][0], acc[mi][ni + 2], 0, 0, 0);
                acc[mi][ni + 2] = __builtin_amdgcn_mfma_f32_16x16x32_bf16(aL[mi][1], bR[ni][1], acc[mi][ni + 2], 0, 0, 0);
            }
        PH_END
        PH_BAR

        // ph7: read aH (Y) ; stage B0(2i+3)->Y
#pragma unroll
        for (int mi = 0; mi < 4; ++mi) { aH[mi][0] = rdA(Ya, mi + 4, 0); aH[mi][1] = rdA(Ya, mi + 4, 1); }
        if (sg) { stageB(2 * i + 3, 1, 0); stageB(2 * i + 3, 1, 1); }
        PH_TOP
#pragma unroll
        for (int mi = 0; mi < 4; ++mi)
#pragma unroll
            for (int ni = 0; ni < 2; ++ni) {
                acc[mi + 4][ni] = __builtin_amdgcn_mfma_f32_16x16x32_bf16(aH[mi][0], bL[ni][0], acc[mi + 4][ni], 0, 0, 0);
                acc[mi + 4][ni] = __builtin_amdgcn_mfma_f32_16x16x32_bf16(aH[mi][1], bL[ni][1], acc[mi + 4][ni], 0, 0, 0);
            }
        PH_END
        PH_BAR

        // ph8: stage A0(2i+3)->Y ; vmcnt
        if (sg) { stageA(2 * i + 3, 1, 0); stageA(2 * i + 3, 1, 1); }
        PH_TOP
#pragma unroll
        for (int mi = 0; mi < 4; ++mi)
#pragma unroll
            for (int ni = 0; ni < 2; ++ni) {
                acc[mi + 4][ni + 2] = __builtin_amdgcn_mfma_f32_16x16x32_bf16(aH[mi][0], bR[ni][0], acc[mi + 4][ni + 2], 0, 0, 0);
                acc[mi + 4][ni + 2] = __builtin_amdgcn_mfma_f32_16x16x32_bf16(aH[mi][1], bR[ni][1], acc[mi + 4][ni + 2], 0, 0, 0);
            }
        PH_END
        if (sg) asm volatile("s_waitcnt vmcnt(4)" ::: "memory");
        else    asm volatile("s_waitcnt vmcnt(0)" ::: "memory");
        PH_BAR
    }

    // fused epilogue: out = leaky(m*y + nw*noise + bias) * sqrt(2), NCHW
    float nw = ldin(nwp, 0, isbf);
    unsigned short* out16 = (unsigned short*)out;
    float* outf = (float*)out;
#pragma unroll
    for (int mf = 0; mf < 8; ++mf) {
        int cobase = co0 + (wm << 7) + (mf << 4) + (hi << 2);
        f32x4 mv = *(const f32x4*)&mmod[b * COUT_ + cobase];
        float bb[4];
#pragma unroll
        for (int r = 0; r < 4; ++r) bb[r] = ldin(bias, cobase + r, isbf);
#pragma unroll
        for (int nf = 0; nf < 4; ++nf) {
            int pix = pl0 + (wn << 6) + (nf << 4) + lr;
            float nv = nw * ldin(noise, b * NPIX + pix, isbf);
#pragma unroll
            for (int r = 0; r < 4; ++r) {
                float v = acc[mf][nf][r] * mv[r] + nv + bb[r];
                v = (v < 0.f ? v * 0.2f : v) * 1.41421356237f;
                size_t oidx = ((size_t)(b * COUT_ + cobase + r)) * NPIX + pix;
                if (isbf) out16[oidx] = f2bf(v);
                else      outf[oidx]  = v;
            }
        }
    }
}

extern "C" void kernel_launch(void* const* d_in, const int* in_sizes, int n_in,
                              void* d_out, int out_size, void* d_ws, size_t ws_size,
                              hipStream_t stream) {
    const void* x      = d_in[0];
    const void* style  = d_in[1];
    const void* noise  = d_in[2];
    const void* kin    = d_in[3];
    const void* sscale = d_in[4];
    const void* bias   = d_in[5];
    const void* nwp    = d_in[6];

    char* ws = (char*)d_ws;
    int* flag = (int*)ws;
    const size_t xtp_off  = 256;
    const size_t xtp_bytes = (size_t)B_ * PADW * PADW * CIN_ * 2;
    const size_t wt_bytes  = (size_t)COUT_ * KTOT * 2;
    unsigned short* xtp = (unsigned short*)(ws + xtp_off);
    unsigned short* wtr = (unsigned short*)(ws + xtp_off + xtp_bytes);
    float* mmod         = (float*)(ws + xtp_off + xtp_bytes + wt_bytes);

    detect_dtype<<<1, 256, 0, stream>>>((const unsigned int*)style, flag);
    halo_zero<<<dim3(260, 8), 256, 0, stream>>>(xtp);
    wt_transpose<<<dim3(8, 72), 256, 0, stream>>>(kin, wtr, flag);
    xpose<<<dim3(8, 64, 8), 256, 0, stream>>>(x, xtp, flag);
    mod_kernel<<<512, 256, 0, stream>>>(style, sscale, wtr, mmod, flag);
    conv_gemm<<<256, 512, 0, stream>>>(wtr, xtp, mmod, noise, bias, nwp, d_out, flag);
}

// Round 12
// 185.848 us; speedup vs baseline: 1.0940x; 1.0129x over previous
//
#include <hip/hip_runtime.h>

#define B_     8
#define CIN_   512
#define COUT_  512
#define HW_    64
#define SDIM_  512
#define NPIX   4096      // pixels per image
#define KTOT   4608      // 9*512
#define PADW   66

typedef __attribute__((ext_vector_type(4))) float f32x4;
typedef __attribute__((ext_vector_type(8))) short bf16x8;
typedef __attribute__((ext_vector_type(8))) unsigned short u16x8;

__device__ __forceinline__ float bf2f(unsigned short b) {
    unsigned int u = ((unsigned int)b) << 16;
    return __builtin_bit_cast(float, u);
}
__device__ __forceinline__ unsigned short f2bf(float f) {
    unsigned int u = __builtin_bit_cast(unsigned int, f);
    return (unsigned short)((u + 0x7fffu + ((u >> 16) & 1u)) >> 16);
}
__device__ __forceinline__ float ldin(const void* p, size_t i, int isbf) {
    return isbf ? bf2f(((const unsigned short*)p)[i]) : ((const float*)p)[i];
}

#define GLD16(g, l) __builtin_amdgcn_global_load_lds( \
    (__attribute__((address_space(1))) void*)(g),     \
    (__attribute__((address_space(3))) void*)(l), 16, 0, 0)

// ---------------- dtype detection (unchanged, verified) ----------------
__global__ void detect_dtype(const unsigned int* __restrict__ style_u32,
                             int* __restrict__ flag) {
    int t = threadIdx.x;
    unsigned int w = style_u32[t * 4];
    int e = (w >> 7) & 0xFF;
    int isbf = (e >= 110 && e <= 140) ? 1 : 0;
    __shared__ int cnt;
    if (t == 0) cnt = 0;
    __syncthreads();
    atomicAdd(&cnt, isbf);
    __syncthreads();
    if (t == 0) *flag = (cnt >= 128) ? 1 : 0;
}

// ---------------- zero halo ring of xtp2 [b][cit][66][66][64] ----------------
__global__ void halo_zero(unsigned int* __restrict__ xtp2u) {
    int idx = blockIdx.x;        // 0..259 ring positions
    int b = blockIdx.y;
    int y, x;
    if (idx < 66)       { y = 0;  x = idx; }
    else if (idx < 132) { y = 65; x = idx - 66; }
    else if (idx < 196) { x = 0;  y = idx - 131; }
    else                { x = 65; y = idx - 195; }
    int t = threadIdx.x;          // 256 = 8 cit x 32 u32 (one 64-elem cell = 32 u32)
    int cit = t >> 5, j = t & 31;
    size_t u32i = ((((size_t)(b * 8 + cit) * 66 + y) * 66 + x) << 5) + j;
    xtp2u[u32i] = 0;
}

// ---------------- kernel (k,co) -> Wt (co,k) transpose (unchanged) ----------------
__global__ void wt_transpose(const void* __restrict__ kin,
                             unsigned short* __restrict__ wt,
                             const int* __restrict__ flag) {
    __shared__ __align__(16) unsigned short tile[64][72];
    int isbf = *flag;
    int t = threadIdx.x;
    int co0 = blockIdx.x * 64;
    int k0  = blockIdx.y * 64;
    int r = t >> 2, c16 = (t & 3) << 4;
    if (isbf) {
        const unsigned short* src = (const unsigned short*)kin + (size_t)(k0 + r) * COUT_ + co0 + c16;
        *(u16x8*)&tile[r][c16]     = *(const u16x8*)src;
        *(u16x8*)&tile[r][c16 + 8] = *(const u16x8*)(src + 8);
    } else {
        const float* src = (const float*)kin + (size_t)(k0 + r) * COUT_ + co0 + c16;
#pragma unroll
        for (int q = 0; q < 4; ++q) {
            f32x4 v = *(const f32x4*)(src + q * 4);
#pragma unroll
            for (int j = 0; j < 4; ++j) tile[r][c16 + q * 4 + j] = f2bf(v[j]);
        }
    }
    __syncthreads();
    int c = t >> 2, r16 = (t & 3) << 4;
    u16x8 w0, w1;
#pragma unroll
    for (int j = 0; j < 8; ++j) { w0[j] = tile[r16 + j][c]; w1[j] = tile[r16 + 8 + j][c]; }
    unsigned short* dst = wt + (size_t)(co0 + c) * KTOT + k0 + r16;
    *(u16x8*)dst       = w0;
    *(u16x8*)(dst + 8) = w1;
}

// ---------------- x NCHW -> padded bf16 ci-tile-major [b][cit][66][66][64] ----------------
__global__ void xpose(const void* __restrict__ x,
                      unsigned short* __restrict__ xtp2,
                      const int* __restrict__ flag) {
    __shared__ __align__(16) unsigned short tile[64][72];
    int isbf = *flag;
    int t = threadIdx.x;
    int cit = blockIdx.x;
    int y   = blockIdx.y;
    int b   = blockIdx.z;
    int ci_l = t >> 2, xo = (t & 3) << 4;
    size_t srcoff = (((size_t)(b * CIN_ + cit * 64 + ci_l)) * HW_ + y) * HW_ + xo;
    if (isbf) {
        const unsigned short* src = (const unsigned short*)x + srcoff;
        *(u16x8*)&tile[ci_l][xo]     = *(const u16x8*)src;
        *(u16x8*)&tile[ci_l][xo + 8] = *(const u16x8*)(src + 8);
    } else {
        const float* src = (const float*)x + srcoff;
#pragma unroll
        for (int q = 0; q < 4; ++q) {
            f32x4 v = *(const f32x4*)(src + q * 4);
#pragma unroll
            for (int j = 0; j < 4; ++j) tile[ci_l][xo + q * 4 + j] = f2bf(v[j]);
        }
    }
    __syncthreads();
    int xl = t >> 2, cio = (t & 3) << 4;
    u16x8 w0, w1;
#pragma unroll
    for (int j = 0; j < 8; ++j) { w0[j] = tile[cio + j][xl]; w1[j] = tile[cio + 8 + j][xl]; }
    unsigned short* dst =
        xtp2 + ((((size_t)(b * 8 + cit) * 66 + (y + 1)) * 66 + (xl + 1)) << 6) + cio;
    *(u16x8*)dst       = w0;
    *(u16x8*)(dst + 8) = w1;
}

// ---------------- mod scale (unchanged) ----------------
__global__ void mod_kernel(const void* __restrict__ style,
                           const void* __restrict__ sscale,
                           const unsigned short* __restrict__ wt,
                           float* __restrict__ mmod,
                           const int* __restrict__ flag) {
    int isbf = *flag;
    int co = blockIdx.x, t = threadIdx.x;
    int lane = t & 63, wid = t >> 6;
    float k2 = 0.f;
    const unsigned short* wr = wt + (size_t)co * KTOT;
    for (int k = t; k < KTOT; k += 256) { float v = bf2f(wr[k]); k2 += v * v; }
    float sb[B_];
#pragma unroll
    for (int b = 0; b < B_; ++b) sb[b] = 0.f;
    for (int sd = t; sd < SDIM_; sd += 256) {
        float ss = ldin(sscale, (size_t)sd * COUT_ + co, isbf);
#pragma unroll
        for (int b = 0; b < B_; ++b) sb[b] += ldin(style, b * SDIM_ + sd, isbf) * ss;
    }
    __shared__ float red[4][9];
    float vals[9];
    vals[0] = k2;
#pragma unroll
    for (int b = 0; b < B_; ++b) vals[1 + b] = sb[b];
#pragma unroll
    for (int q = 0; q < 9; ++q) {
        float v = vals[q];
        for (int off = 32; off; off >>= 1) v += __shfl_down(v, off);
        if (lane == 0) red[wid][q] = v;
    }
    __syncthreads();
    if (t < B_) {
        int b = t;
        float k2t = red[0][0] + red[1][0] + red[2][0] + red[3][0];
        float s   = red[0][1 + b] + red[1][1 + b] + red[2][1 + b] + red[3][1 + b];
        float sp1 = s + 1.f;
        mmod[b * COUT_ + co] = sp1 * rsqrtf(sp1 * sp1 * k2t + 1e-8f);
    }
}

// ---------------- implicit-GEMM conv: ci-outer, LDS-resident B-window ----------------
// K order: cit (8) outer x khw (9) inner. Per cit: B spatial window (6 rows x
// 66 cols x 64 ci = 50.7KB) staged ONCE into Win[6][72][64] (slot-XOR swizzle),
// read with (kh,kw) shifts for all 9 khw tiles. Per tile: only A double-buffer
// (stage A(t+1), 4 gld16/wave; 2 fences + 1 barrier). B staging removed from
// the per-tile path; B HBM traffic /5.
__global__ __launch_bounds__(512, 2) void conv_gemm(
    const unsigned short* __restrict__ wt,
    const unsigned short* __restrict__ xtp2,
    const float* __restrict__ mmod,
    const void* __restrict__ noise,
    const void* __restrict__ bias,
    const void* __restrict__ nwp,
    void* __restrict__ out,
    const int* __restrict__ flag) {
    __shared__ __align__(1024) unsigned short Asm[2][256 * 64];   // 64 KiB
    __shared__ __align__(1024) unsigned short Win[6 * 72 * 64];   // 55.3 KiB
    int isbf = *flag;
    int tid = threadIdx.x;
    int lane = tid & 63, wid = tid >> 6;
    int lr = lane & 15, hi = lane >> 4;
    int wm = wid >> 2, wn = wid & 3;          // 2 x 4 wave grid; wave = 128co x 64px(row wn)

    int bid = blockIdx.x;
    int swz = (bid & 7) * 32 + (bid >> 3);    // XCD-chunked bijective (256 % 8 == 0)
    int gy = swz >> 7;
    int nb = swz & 127;
    int b  = nb >> 4;
    int nt = nb & 15;
    int pl0 = nt << 8;                        // 256 pixels = 4 image rows
    int h0  = pl0 >> 6;
    int co0 = gy << 8;

    f32x4 acc[8][4];
#pragma unroll
    for (int i = 0; i < 8; ++i)
#pragma unroll
        for (int j = 0; j < 4; ++j) acc[i][j] = (f32x4){0.f, 0.f, 0.f, 0.f};

    int rsub = lane >> 3;
    int ce_src = ((lane & 7) ^ rsub) << 3;    // A pre-swizzled source column (elems)
    int swzr = (lane & 7) << 3;               // A read XOR
    // window stage: per-lane source offset (elems). cell w = g*8 + (lane>>3);
    // slot s = lane&7 holds src chunk (s ^ (w&7)); w&7 == (lane>>3)&7 since 8|g*8.
    int wsrc = (rsub << 6) + (((lane & 7) ^ (rsub & 7)) << 3);
    int l7 = lane & 7;
    int px[4];                                 // per-ni pixel-column bases (elems)
#pragma unroll
    for (int ni = 0; ni < 4; ++ni) px[ni] = ((ni << 4) + lr) << 6;

    auto stageA = [&](int koff, int pp, int q) {
        const unsigned short* srcA =
            wt + (size_t)(co0 + (q << 6) + (wid << 3) + rsub) * KTOT + koff + ce_src;
        GLD16(srcA, (char*)&Asm[pp][0] + (q << 13) + (wid << 10));
    };
    auto stage_win = [&](int cit) {
        size_t base = ((size_t)(b * 8 + cit) * 66 + h0) * (66 * 64);
        for (int idx = wid; idx < 54; idx += 8) {       // 6 rows x 9 chunks
            int r = idx / 9, g = idx - r * 9;
            const unsigned short* src = xtp2 + base + (size_t)r * (66 * 64) + (g << 9) + wsrc;
            GLD16(src, (char*)Win + r * 9216 + (g << 10));
        }
    };

    // prologue: window(cit=0) + A(tile 0, koff=0)
    stage_win(0);
#pragma unroll
    for (int q = 0; q < 4; ++q) stageA(0, 0, q);
    asm volatile("s_waitcnt vmcnt(0)" ::: "memory");
    __builtin_amdgcn_s_barrier();
    asm volatile("" ::: "memory");

    int t = 0;
    for (int cit = 0; cit < 8; ++cit) {
        if (cit > 0) {
            stage_win(cit);                    // window readers retired at prev tile end
            asm volatile("s_waitcnt vmcnt(0)" ::: "memory");
            __builtin_amdgcn_s_barrier();
            asm volatile("" ::: "memory");
        }
        for (int khw = 0; khw < 9; ++khw, ++t) {
            int p = t & 1, pn = p ^ 1;
            const unsigned short* As = &Asm[p][0];
            int kh = (khw >= 6) ? 2 : ((khw >= 3) ? 1 : 0);
            int kw = khw - kh * 3;
            int BD = (((wn + kh) * 72) + kw) << 6;         // window base (uniform/wave)
            int xv = ((l7 + kw) & 7) << 3;                 // B read XOR (per-lane)

            // stage A(t+1) -> pn (its readers retired one fence+barrier ago)
            if (t < 71) {
                int khw1 = (khw == 8) ? 0 : khw + 1;
                int cit1 = (khw == 8) ? cit + 1 : cit;
                int koff1 = khw1 * 512 + (cit1 << 6);
#pragma unroll
                for (int q = 0; q < 4; ++q) stageA(koff1, pn, q);
            }

            // ---- Q0: a[0-3]k0 x b k0 ----
            bf16x8 a0[4], bk0[4];
            int kc0 = (hi << 3), kc1 = 32 + (hi << 3);
#pragma unroll
            for (int i = 0; i < 4; ++i)
                a0[i] = *(const bf16x8*)&As[(((wm << 7) + (i << 4) + lr) << 6) + (kc0 ^ swzr)];
#pragma unroll
            for (int ni = 0; ni < 4; ++ni)
                bk0[ni] = *(const bf16x8*)&Win[BD + px[ni] + (kc0 ^ xv)];
            __builtin_amdgcn_s_setprio(1);
#pragma unroll
            for (int mf = 0; mf < 4; ++mf)
#pragma unroll
                for (int nf = 0; nf < 4; ++nf)
                    acc[mf][nf] = __builtin_amdgcn_mfma_f32_16x16x32_bf16(a0[mf], bk0[nf], acc[mf][nf], 0, 0, 0);
            __builtin_amdgcn_s_setprio(0);

            // ---- Q1: a[4-7]k0 x b k0 ----
            bf16x8 a1[4];
#pragma unroll
            for (int i = 0; i < 4; ++i)
                a1[i] = *(const bf16x8*)&As[(((wm << 7) + ((i + 4) << 4) + lr) << 6) + (kc0 ^ swzr)];
            __builtin_amdgcn_s_setprio(1);
#pragma unroll
            for (int mf = 0; mf < 4; ++mf)
#pragma unroll
                for (int nf = 0; nf < 4; ++nf)
                    acc[mf + 4][nf] = __builtin_amdgcn_mfma_f32_16x16x32_bf16(a1[mf], bk0[nf], acc[mf + 4][nf], 0, 0, 0);
            __builtin_amdgcn_s_setprio(0);

            // ---- Q2: a[0-3]k1 x b k1 ----
            bf16x8 a2[4], bk1[4];
#pragma unroll
            for (int i = 0; i < 4; ++i)
                a2[i] = *(const bf16x8*)&As[(((wm << 7) + (i << 4) + lr) << 6) + (kc1 ^ swzr)];
#pragma unroll
            for (int ni = 0; ni < 4; ++ni)
                bk1[ni] = *(const bf16x8*)&Win[BD + px[ni] + (kc1 ^ xv)];
            __builtin_amdgcn_s_setprio(1);
#pragma unroll
            for (int mf = 0; mf < 4; ++mf)
#pragma unroll
                for (int nf = 0; nf < 4; ++nf)
                    acc[mf][nf] = __builtin_amdgcn_mfma_f32_16x16x32_bf16(a2[mf], bk1[nf], acc[mf][nf], 0, 0, 0);
            __builtin_amdgcn_s_setprio(0);

            // ---- Q3: a[4-7]k1 x b k1 ----
            bf16x8 a3[4];
#pragma unroll
            for (int i = 0; i < 4; ++i)
                a3[i] = *(const bf16x8*)&As[(((wm << 7) + ((i + 4) << 4) + lr) << 6) + (kc1 ^ swzr)];
            __builtin_amdgcn_s_setprio(1);
#pragma unroll
            for (int mf = 0; mf < 4; ++mf)
#pragma unroll
                for (int nf = 0; nf < 4; ++nf)
                    acc[mf + 4][nf] = __builtin_amdgcn_mfma_f32_16x16x32_bf16(a3[mf], bk1[nf], acc[mf + 4][nf], 0, 0, 0);
            __builtin_amdgcn_s_setprio(0);

            // ---- tile boundary ----
            asm volatile("s_waitcnt lgkmcnt(0)" ::: "memory");   // my LDS reads retired
            if (t < 71) asm volatile("s_waitcnt vmcnt(0)" ::: "memory");  // A(t+1) landed
            __builtin_amdgcn_s_barrier();
            asm volatile("" ::: "memory");
        }
    }

    // fused epilogue: out = leaky(m*y + nw*noise + bias) * sqrt(2), NCHW
    float nw = ldin(nwp, 0, isbf);
    unsigned short* out16 = (unsigned short*)out;
    float* outf = (float*)out;
#pragma unroll
    for (int mf = 0; mf < 8; ++mf) {
        int cobase = co0 + (wm << 7) + (mf << 4) + (hi << 2);
        f32x4 mv = *(const f32x4*)&mmod[b * COUT_ + cobase];
        float bb[4];
#pragma unroll
        for (int r = 0; r < 4; ++r) bb[r] = ldin(bias, cobase + r, isbf);
#pragma unroll
        for (int nf = 0; nf < 4; ++nf) {
            int pix = pl0 + (wn << 6) + (nf << 4) + lr;
            float nv = nw * ldin(noise, b * NPIX + pix, isbf);
#pragma unroll
            for (int r = 0; r < 4; ++r) {
                float v = acc[mf][nf][r] * mv[r] + nv + bb[r];
                v = (v < 0.f ? v * 0.2f : v) * 1.41421356237f;
                size_t oidx = ((size_t)(b * COUT_ + cobase + r)) * NPIX + pix;
                if (isbf) out16[oidx] = f2bf(v);
                else      outf[oidx]  = v;
            }
        }
    }
}

extern "C" void kernel_launch(void* const* d_in, const int* in_sizes, int n_in,
                              void* d_out, int out_size, void* d_ws, size_t ws_size,
                              hipStream_t stream) {
    const void* x      = d_in[0];
    const void* style  = d_in[1];
    const void* noise  = d_in[2];
    const void* kin    = d_in[3];
    const void* sscale = d_in[4];
    const void* bias   = d_in[5];
    const void* nwp    = d_in[6];

    char* ws = (char*)d_ws;
    int* flag = (int*)ws;
    const size_t xtp_off   = 256;
    const size_t xtp_bytes = (size_t)B_ * 8 * 66 * 66 * 64 * 2;   // 35,684,352 (ci-tile-major)
    const size_t pad       = 4096;                                 // stage_win overrun pad
    const size_t wt_bytes  = (size_t)COUT_ * KTOT * 2;
    unsigned short* xtp2 = (unsigned short*)(ws + xtp_off);
    unsigned short* wtr  = (unsigned short*)(ws + xtp_off + xtp_bytes + pad);
    float* mmod          = (float*)(ws + xtp_off + xtp_bytes + pad + wt_bytes);

    detect_dtype<<<1, 256, 0, stream>>>((const unsigned int*)style, flag);
    halo_zero<<<dim3(260, 8), 256, 0, stream>>>((unsigned int*)xtp2);
    wt_transpose<<<dim3(8, 72), 256, 0, stream>>>(kin, wtr, flag);
    xpose<<<dim3(8, 64, 8), 256, 0, stream>>>(x, xtp2, flag);
    mod_kernel<<<512, 256, 0, stream>>>(style, sscale, wtr, mmod, flag);
    conv_gemm<<<256, 512, 0, stream>>>(wtr, xtp2, mmod, noise, bias, nwp, d_out, flag);
}

// Round 13
// 182.141 us; speedup vs baseline: 1.1162x; 1.0204x over previous
//
#include <hip/hip_runtime.h>

#define B_     8
#define CIN_   512
#define COUT_  512
#define HW_    64
#define SDIM_  512
#define NPIX   4096      // pixels per image
#define KTOT   4608      // 9*512
#define PADW   66

typedef __attribute__((ext_vector_type(4))) float f32x4;
typedef __attribute__((ext_vector_type(8))) short bf16x8;
typedef __attribute__((ext_vector_type(8))) unsigned short u16x8;

__device__ __forceinline__ float bf2f(unsigned short b) {
    unsigned int u = ((unsigned int)b) << 16;
    return __builtin_bit_cast(float, u);
}
__device__ __forceinline__ unsigned short f2bf(float f) {
    unsigned int u = __builtin_bit_cast(unsigned int, f);
    return (unsigned short)((u + 0x7fffu + ((u >> 16) & 1u)) >> 16);
}
__device__ __forceinline__ float ldin(const void* p, size_t i, int isbf) {
    return isbf ? bf2f(((const unsigned short*)p)[i]) : ((const float*)p)[i];
}

#define GLD16(g, l) __builtin_amdgcn_global_load_lds( \
    (__attribute__((address_space(1))) void*)(g),     \
    (__attribute__((address_space(3))) void*)(l), 16, 0, 0)

// ---------------- dtype detection (unchanged, verified) ----------------
__global__ void detect_dtype(const unsigned int* __restrict__ style_u32,
                             int* __restrict__ flag) {
    int t = threadIdx.x;
    unsigned int w = style_u32[t * 4];
    int e = (w >> 7) & 0xFF;
    int isbf = (e >= 110 && e <= 140) ? 1 : 0;
    __shared__ int cnt;
    if (t == 0) cnt = 0;
    __syncthreads();
    atomicAdd(&cnt, isbf);
    __syncthreads();
    if (t == 0) *flag = (cnt >= 128) ? 1 : 0;
}

// ---------------- zero halo ring of xtp2 [b][cit][66][66][64] ----------------
__global__ void halo_zero(unsigned int* __restrict__ xtp2u) {
    int idx = blockIdx.x;        // 0..259 ring positions
    int b = blockIdx.y;
    int y, x;
    if (idx < 66)       { y = 0;  x = idx; }
    else if (idx < 132) { y = 65; x = idx - 66; }
    else if (idx < 196) { x = 0;  y = idx - 131; }
    else                { x = 65; y = idx - 195; }
    int t = threadIdx.x;          // 256 = 8 cit x 32 u32 (one 64-elem cell = 32 u32)
    int cit = t >> 5, j = t & 31;
    size_t u32i = ((((size_t)(b * 8 + cit) * 66 + y) * 66 + x) << 5) + j;
    xtp2u[u32i] = 0;
}

// ---------------- kernel (k,co) -> Wt (co,k) transpose (unchanged) ----------------
__global__ void wt_transpose(const void* __restrict__ kin,
                             unsigned short* __restrict__ wt,
                             const int* __restrict__ flag) {
    __shared__ __align__(16) unsigned short tile[64][72];
    int isbf = *flag;
    int t = threadIdx.x;
    int co0 = blockIdx.x * 64;
    int k0  = blockIdx.y * 64;
    int r = t >> 2, c16 = (t & 3) << 4;
    if (isbf) {
        const unsigned short* src = (const unsigned short*)kin + (size_t)(k0 + r) * COUT_ + co0 + c16;
        *(u16x8*)&tile[r][c16]     = *(const u16x8*)src;
        *(u16x8*)&tile[r][c16 + 8] = *(const u16x8*)(src + 8);
    } else {
        const float* src = (const float*)kin + (size_t)(k0 + r) * COUT_ + co0 + c16;
#pragma unroll
        for (int q = 0; q < 4; ++q) {
            f32x4 v = *(const f32x4*)(src + q * 4);
#pragma unroll
            for (int j = 0; j < 4; ++j) tile[r][c16 + q * 4 + j] = f2bf(v[j]);
        }
    }
    __syncthreads();
    int c = t >> 2, r16 = (t & 3) << 4;
    u16x8 w0, w1;
#pragma unroll
    for (int j = 0; j < 8; ++j) { w0[j] = tile[r16 + j][c]; w1[j] = tile[r16 + 8 + j][c]; }
    unsigned short* dst = wt + (size_t)(co0 + c) * KTOT + k0 + r16;
    *(u16x8*)dst       = w0;
    *(u16x8*)(dst + 8) = w1;
}

// ---------------- x NCHW -> padded bf16 ci-tile-major [b][cit][66][66][64] ----------------
__global__ void xpose(const void* __restrict__ x,
                      unsigned short* __restrict__ xtp2,
                      const int* __restrict__ flag) {
    __shared__ __align__(16) unsigned short tile[64][72];
    int isbf = *flag;
    int t = threadIdx.x;
    int cit = blockIdx.x;
    int y   = blockIdx.y;
    int b   = blockIdx.z;
    int ci_l = t >> 2, xo = (t & 3) << 4;
    size_t srcoff = (((size_t)(b * CIN_ + cit * 64 + ci_l)) * HW_ + y) * HW_ + xo;
    if (isbf) {
        const unsigned short* src = (const unsigned short*)x + srcoff;
        *(u16x8*)&tile[ci_l][xo]     = *(const u16x8*)src;
        *(u16x8*)&tile[ci_l][xo + 8] = *(const u16x8*)(src + 8);
    } else {
        const float* src = (const float*)x + srcoff;
#pragma unroll
        for (int q = 0; q < 4; ++q) {
            f32x4 v = *(const f32x4*)(src + q * 4);
#pragma unroll
            for (int j = 0; j < 4; ++j) tile[ci_l][xo + q * 4 + j] = f2bf(v[j]);
        }
    }
    __syncthreads();
    int xl = t >> 2, cio = (t & 3) << 4;
    u16x8 w0, w1;
#pragma unroll
    for (int j = 0; j < 8; ++j) { w0[j] = tile[cio + j][xl]; w1[j] = tile[cio + 8 + j][xl]; }
    unsigned short* dst =
        xtp2 + ((((size_t)(b * 8 + cit) * 66 + (y + 1)) * 66 + (xl + 1)) << 6) + cio;
    *(u16x8*)dst       = w0;
    *(u16x8*)(dst + 8) = w1;
}

// ---------------- mod scale (unchanged) ----------------
__global__ void mod_kernel(const void* __restrict__ style,
                           const void* __restrict__ sscale,
                           const unsigned short* __restrict__ wt,
                           float* __restrict__ mmod,
                           const int* __restrict__ flag) {
    int isbf = *flag;
    int co = blockIdx.x, t = threadIdx.x;
    int lane = t & 63, wid = t >> 6;
    float k2 = 0.f;
    const unsigned short* wr = wt + (size_t)co * KTOT;
    for (int k = t; k < KTOT; k += 256) { float v = bf2f(wr[k]); k2 += v * v; }
    float sb[B_];
#pragma unroll
    for (int b = 0; b < B_; ++b) sb[b] = 0.f;
    for (int sd = t; sd < SDIM_; sd += 256) {
        float ss = ldin(sscale, (size_t)sd * COUT_ + co, isbf);
#pragma unroll
        for (int b = 0; b < B_; ++b) sb[b] += ldin(style, b * SDIM_ + sd, isbf) * ss;
    }
    __shared__ float red[4][9];
    float vals[9];
    vals[0] = k2;
#pragma unroll
    for (int b = 0; b < B_; ++b) vals[1 + b] = sb[b];
#pragma unroll
    for (int q = 0; q < 9; ++q) {
        float v = vals[q];
        for (int off = 32; off; off >>= 1) v += __shfl_down(v, off);
        if (lane == 0) red[wid][q] = v;
    }
    __syncthreads();
    if (t < B_) {
        int b = t;
        float k2t = red[0][0] + red[1][0] + red[2][0] + red[3][0];
        float s   = red[0][1 + b] + red[1][1 + b] + red[2][1 + b] + red[3][1 + b];
        float sp1 = s + 1.f;
        mmod[b * COUT_ + co] = sp1 * rsqrtf(sp1 * sp1 * k2t + 1e-8f);
    }
}

// ---------------- implicit-GEMM conv: ci-outer, B-window, SGB read/MFMA interleave ----------------
// Per tile (one scheduling region, no mid-tile fences):
//   VMEMx4 (stage A t+1) ; DS_READx8 (a0,bk0) ; {DS_READ 1, MFMA 4}x4 (Q0 || a1)
//   {DS_READ 1, MFMA 2}x8 (Q1 || a2,bk1) ; {DS_READ 1, MFMA 4}x4 (Q2 || a3) ; MFMA x16 (Q3)
// The LDS-port drain (24 b128/wave/tile) now runs UNDER the MFMA pipe instead of
// serial bursts (the 36-41% MfmaUtil invariant across 9 schedule variants).
__global__ __launch_bounds__(512, 2) void conv_gemm(
    const unsigned short* __restrict__ wt,
    const unsigned short* __restrict__ xtp2,
    const float* __restrict__ mmod,
    const void* __restrict__ noise,
    const void* __restrict__ bias,
    const void* __restrict__ nwp,
    void* __restrict__ out,
    const int* __restrict__ flag) {
    __shared__ __align__(1024) unsigned short Asm[2][256 * 64];   // 64 KiB
    __shared__ __align__(1024) unsigned short Win[6 * 72 * 64];   // 55.3 KiB
    int isbf = *flag;
    int tid = threadIdx.x;
    int lane = tid & 63, wid = tid >> 6;
    int lr = lane & 15, hi = lane >> 4;
    int wm = wid >> 2, wn = wid & 3;          // 2 x 4 wave grid; wave = 128co x 64px(row wn)

    int bid = blockIdx.x;
    int swz = (bid & 7) * 32 + (bid >> 3);    // XCD-chunked bijective (256 % 8 == 0)
    int gy = swz >> 7;
    int nb = swz & 127;
    int b  = nb >> 4;
    int nt = nb & 15;
    int pl0 = nt << 8;                        // 256 pixels = 4 image rows
    int h0  = pl0 >> 6;
    int co0 = gy << 8;

    f32x4 acc[8][4];
#pragma unroll
    for (int i = 0; i < 8; ++i)
#pragma unroll
        for (int j = 0; j < 4; ++j) acc[i][j] = (f32x4){0.f, 0.f, 0.f, 0.f};

    int rsub = lane >> 3;
    int ce_src = ((lane & 7) ^ rsub) << 3;    // A pre-swizzled source column (elems)
    int swzr = (lane & 7) << 3;               // A read XOR
    int wsrc = (rsub << 6) + (((lane & 7) ^ (rsub & 7)) << 3);  // window stage src (elems)
    int l7 = lane & 7;
    int px[4];                                 // per-ni pixel-column bases (elems)
#pragma unroll
    for (int ni = 0; ni < 4; ++ni) px[ni] = ((ni << 4) + lr) << 6;

    auto stageA = [&](int koff, int pp, int q) {
        const unsigned short* srcA =
            wt + (size_t)(co0 + (q << 6) + (wid << 3) + rsub) * KTOT + koff + ce_src;
        GLD16(srcA, (char*)&Asm[pp][0] + (q << 13) + (wid << 10));
    };
    auto stage_win = [&](int cit) {
        size_t base = ((size_t)(b * 8 + cit) * 66 + h0) * (66 * 64);
        for (int idx = wid; idx < 54; idx += 8) {       // 6 rows x 9 chunks
            int r = idx / 9, g = idx - r * 9;
            const unsigned short* src = xtp2 + base + (size_t)r * (66 * 64) + (g << 9) + wsrc;
            GLD16(src, (char*)Win + r * 9216 + (g << 10));
        }
    };

    // prologue: window(cit=0) + A(tile 0, koff=0)
    stage_win(0);
#pragma unroll
    for (int q = 0; q < 4; ++q) stageA(0, 0, q);
    asm volatile("s_waitcnt vmcnt(0)" ::: "memory");
    __builtin_amdgcn_s_barrier();
    asm volatile("" ::: "memory");

    int t = 0;
    for (int cit = 0; cit < 8; ++cit) {
        if (cit > 0) {
            stage_win(cit);                    // window readers retired at prev tile end
            asm volatile("s_waitcnt vmcnt(0)" ::: "memory");
            __builtin_amdgcn_s_barrier();
            asm volatile("" ::: "memory");
        }
        for (int khw = 0; khw < 9; ++khw, ++t) {
            int p = t & 1, pn = p ^ 1;
            const unsigned short* As = &Asm[p][0];
            int kh = (khw >= 6) ? 2 : ((khw >= 3) ? 1 : 0);
            int kw = khw - kh * 3;
            int BD = (((wn + kh) * 72) + kw) << 6;         // window base (uniform/wave)
            int xv = ((l7 + kw) & 7) << 3;                 // B read XOR (per-lane)

            // stage A(t+1) -> pn (its readers retired one fence+barrier ago)
            if (t < 71) {
                int khw1 = (khw == 8) ? 0 : khw + 1;
                int cit1 = (khw == 8) ? cit + 1 : cit;
                int koff1 = khw1 * 512 + (cit1 << 6);
#pragma unroll
                for (int q = 0; q < 4; ++q) stageA(koff1, pn, q);
            }

            int kc0 = (hi << 3), kc1 = 32 + (hi << 3);
            // reads (source order; SGB template below interleaves them into MFMA clusters)
            bf16x8 a0[4], bk0[4], a1[4], a2[4], bk1[4], a3[4];
#pragma unroll
            for (int i = 0; i < 4; ++i)
                a0[i] = *(const bf16x8*)&As[(((wm << 7) + (i << 4) + lr) << 6) + (kc0 ^ swzr)];
#pragma unroll
            for (int ni = 0; ni < 4; ++ni)
                bk0[ni] = *(const bf16x8*)&Win[BD + px[ni] + (kc0 ^ xv)];
#pragma unroll
            for (int i = 0; i < 4; ++i)
                a1[i] = *(const bf16x8*)&As[(((wm << 7) + ((i + 4) << 4) + lr) << 6) + (kc0 ^ swzr)];
#pragma unroll
            for (int i = 0; i < 4; ++i)
                a2[i] = *(const bf16x8*)&As[(((wm << 7) + (i << 4) + lr) << 6) + (kc1 ^ swzr)];
#pragma unroll
            for (int ni = 0; ni < 4; ++ni)
                bk1[ni] = *(const bf16x8*)&Win[BD + px[ni] + (kc1 ^ xv)];
#pragma unroll
            for (int i = 0; i < 4; ++i)
                a3[i] = *(const bf16x8*)&As[(((wm << 7) + ((i + 4) << 4) + lr) << 6) + (kc1 ^ swzr)];

            // MFMA clusters
#pragma unroll
            for (int mf = 0; mf < 4; ++mf)
#pragma unroll
                for (int nf = 0; nf < 4; ++nf)
                    acc[mf][nf] = __builtin_amdgcn_mfma_f32_16x16x32_bf16(a0[mf], bk0[nf], acc[mf][nf], 0, 0, 0);
#pragma unroll
            for (int mf = 0; mf < 4; ++mf)
#pragma unroll
                for (int nf = 0; nf < 4; ++nf)
                    acc[mf + 4][nf] = __builtin_amdgcn_mfma_f32_16x16x32_bf16(a1[mf], bk0[nf], acc[mf + 4][nf], 0, 0, 0);
#pragma unroll
            for (int mf = 0; mf < 4; ++mf)
#pragma unroll
                for (int nf = 0; nf < 4; ++nf)
                    acc[mf][nf] = __builtin_amdgcn_mfma_f32_16x16x32_bf16(a2[mf], bk1[nf], acc[mf][nf], 0, 0, 0);
#pragma unroll
            for (int mf = 0; mf < 4; ++mf)
#pragma unroll
                for (int nf = 0; nf < 4; ++nf)
                    acc[mf + 4][nf] = __builtin_amdgcn_mfma_f32_16x16x32_bf16(a3[mf], bk1[nf], acc[mf + 4][nf], 0, 0, 0);

            // ---- SGB schedule template for this region ----
            __builtin_amdgcn_sched_group_barrier(0x010, 4, 0);   // stage VMEM
            __builtin_amdgcn_sched_group_barrier(0x100, 8, 0);   // a0+bk0
#pragma unroll
            for (int r = 0; r < 4; ++r) {                        // Q0 || a1
                __builtin_amdgcn_sched_group_barrier(0x100, 1, 0);
                __builtin_amdgcn_sched_group_barrier(0x008, 4, 0);
            }
#pragma unroll
            for (int r = 0; r < 8; ++r) {                        // Q1 || a2,bk1
                __builtin_amdgcn_sched_group_barrier(0x100, 1, 0);
                __builtin_amdgcn_sched_group_barrier(0x008, 2, 0);
            }
#pragma unroll
            for (int r = 0; r < 4; ++r) {                        // Q2 || a3
                __builtin_amdgcn_sched_group_barrier(0x100, 1, 0);
                __builtin_amdgcn_sched_group_barrier(0x008, 4, 0);
            }
            __builtin_amdgcn_sched_group_barrier(0x008, 16, 0);  // Q3

            // ---- tile boundary ----
            asm volatile("s_waitcnt lgkmcnt(0)" ::: "memory");   // my LDS reads retired
            if (t < 71) asm volatile("s_waitcnt vmcnt(0)" ::: "memory");  // A(t+1) landed
            __builtin_amdgcn_s_barrier();
            asm volatile("" ::: "memory");
        }
    }

    // fused epilogue: out = leaky(m*y + nw*noise + bias) * sqrt(2), NCHW
    float nw = ldin(nwp, 0, isbf);
    unsigned short* out16 = (unsigned short*)out;
    float* outf = (float*)out;
#pragma unroll
    for (int mf = 0; mf < 8; ++mf) {
        int cobase = co0 + (wm << 7) + (mf << 4) + (hi << 2);
        f32x4 mv = *(const f32x4*)&mmod[b * COUT_ + cobase];
        float bb[4];
#pragma unroll
        for (int r = 0; r < 4; ++r) bb[r] = ldin(bias, cobase + r, isbf);
#pragma unroll
        for (int nf = 0; nf < 4; ++nf) {
            int pix = pl0 + (wn << 6) + (nf << 4) + lr;
            float nv = nw * ldin(noise, b * NPIX + pix, isbf);
#pragma unroll
            for (int r = 0; r < 4; ++r) {
                float v = acc[mf][nf][r] * mv[r] + nv + bb[r];
                v = (v < 0.f ? v * 0.2f : v) * 1.41421356237f;
                size_t oidx = ((size_t)(b * COUT_ + cobase + r)) * NPIX + pix;
                if (isbf) out16[oidx] = f2bf(v);
                else      outf[oidx]  = v;
            }
        }
    }
}

extern "C" void kernel_launch(void* const* d_in, const int* in_sizes, int n_in,
                              void* d_out, int out_size, void* d_ws, size_t ws_size,
                              hipStream_t stream) {
    const void* x      = d_in[0];
    const void* style  = d_in[1];
    const void* noise  = d_in[2];
    const void* kin    = d_in[3];
    const void* sscale = d_in[4];
    const void* bias   = d_in[5];
    const void* nwp    = d_in[6];

    char* ws = (char*)d_ws;
    int* flag = (int*)ws;
    const size_t xtp_off   = 256;
    const size_t xtp_bytes = (size_t)B_ * 8 * 66 * 66 * 64 * 2;   // 35,684,352 (ci-tile-major)
    const size_t pad       = 4096;                                 // stage_win overrun pad
    const size_t wt_bytes  = (size_t)COUT_ * KTOT * 2;
    unsigned short* xtp2 = (unsigned short*)(ws + xtp_off);
    unsigned short* wtr  = (unsigned short*)(ws + xtp_off + xtp_bytes + pad);
    float* mmod          = (float*)(ws + xtp_off + xtp_bytes + pad + wt_bytes);

    detect_dtype<<<1, 256, 0, stream>>>((const unsigned int*)style, flag);
    halo_zero<<<dim3(260, 8), 256, 0, stream>>>((unsigned int*)xtp2);
    wt_transpose<<<dim3(8, 72), 256, 0, stream>>>(kin, wtr, flag);
    xpose<<<dim3(8, 64, 8), 256, 0, stream>>>(x, xtp2, flag);
    mod_kernel<<<512, 256, 0, stream>>>(style, sscale, wtr, mmod, flag);
    conv_gemm<<<256, 512, 0, stream>>>(wtr, xtp2, mmod, noise, bias, nwp, d_out, flag);
}